// Round 5
// baseline (113.166 us; speedup 1.0000x reference)
//
#include <hip/hip_runtime.h>

#define IMG    384
#define IMG4   96
#define IMG2   (IMG*IMG)
#define CROP   378
#define NB     64
#define NGRP   12
#define NROWS  32      // crop rows per block
#define SPB    8       // stripes (4 rows each)
#define NTH    448     // 7 waves = 7 row-shifts
#define PSTR   424     // floats per (b,grp) record

__device__ __forceinline__ float wave_sum_f(float v) {
    v += __shfl_down(v, 32);
    v += __shfl_down(v, 16);
    v += __shfl_down(v, 8);
    v += __shfl_down(v, 4);
    v += __shfl_down(v, 2);
    v += __shfl_down(v, 1);
    return v;
}

__device__ __forceinline__ void dec4(unsigned u, float* d) {
    d[0] = (float)( u         & 255u);
    d[1] = (float)((u >>  8)  & 255u);
    d[2] = (float)((u >> 16)  & 255u);
    d[3] = (float)((u >> 24)  & 255u);
}

// Planar LDS: f4 col c (0..95) -> [part=c%3][slot=c/3]; q-window reads are
// dense 16B-stride ds_read_b128 (conflict-free). Mask kept as packed bytes
// (1 u32 per f4-col). 16-row circular buffer: stripe s reads local rows
// [4s,4s+9], stages [4s+10,4s+13] (disjoint mod 16).
__global__ __launch_bounds__(NTH)
void corr_kernel(const float* __restrict__ sr, const float* __restrict__ hr,
                 const float* __restrict__ mk, float* __restrict__ part)
{
    __shared__ float4   lq [16][3][32];   // 24576 B, q = hr*mask
    __shared__ unsigned lmb[16][3][32];   //  6144 B, mask bytes

    const int tid = threadIdx.x;
    // XCD-clustered: all 12 blocks of a batch on one XCD class
    const int id  = blockIdx.x;
    const int c8  = id & 7;
    const int k0  = id >> 3;
    const int b   = c8 + 8 * (k0 / NGRP);
    const int grp = k0 % NGRP;
    const int c0  = grp * NROWS;
    const int vrows = (CROP - c0 < NROWS) ? (CROP - c0) : NROWS;

    const float4* sb4 = (const float4*)(sr + (size_t)b * IMG2);
    const float4* hb4 = (const float4*)(hr + (size_t)b * IMG2);
    const float4* mb4 = (const float4*)(mk + (size_t)b * IMG2);

    const int w    = tid >> 6;        // wave index = row shift i
    const int lane = tid & 63;
    const int l    = lane & 31;       // 12-px chunk (cols 12l..12l+11)
    const int rsel = lane >> 5;       // row-within-pair
    const int l1   = (l + 1) & 31;

    // staging map (tid < 384): one f4 col of one new row
    const int ssub = tid / 96;
    const int sc   = tid % 96;
    const int spt  = sc % 3;
    const int ssl  = sc / 3;

    // edge map: lanes 0..11 of EACH wave handle cols {0..5,378..383} at shift w
    const int ecol = (lane < 6) ? lane : (366 + lane);   // valid when lane<12
    const int ecf  = ecol >> 2;
    const int ept  = ecf % 3;
    const int esl  = ecf / 3;
    const int esub = ecol & 3;

    float aA[7] = {0,0,0,0,0,0,0};
    float aB[7] = {0,0,0,0,0,0,0};
    float aC[7] = {0,0,0,0,0,0,0};
    float aTm = 0.f, aTq = 0.f, aTq2 = 0.f, aSp = 0.f;
    float eM = 0.f, eQ = 0.f, eQ2 = 0.f;

    float4 sA[4], sB[4];              // sr prefetch regs (step0 / step1)
    auto prefetch_sr = [&](int s) {
        #pragma unroll
        for (int step = 0; step < 2; ++step) {
            const int lr = 4 * s + 2 * step + rsel;
            int ir = c0 + lr + 3; if (ir > 380) ir = 380;  // valid rows never clamp
            const size_t so = (size_t)ir * IMG4 + 3 * l;
            float4* D = step ? sB : sA;
            D[0] = sb4[so];     D[1] = sb4[so + 1];
            D[2] = sb4[so + 2]; D[3] = sb4[so + 3];
        }
    };

    // ---- prologue: stage local rows 0..9, prefetch stripe-0 sr ----
    for (int idx = tid; idx < 960; idx += NTH) {
        const int lr = idx / 96, c = idx % 96;
        const int pt = c % 3, sl = c / 3;
        int ir = c0 + lr; if (ir > IMG - 1) ir = IMG - 1;
        const float4 h = hb4[(size_t)ir * IMG4 + c];
        const float4 m = mb4[(size_t)ir * IMG4 + c];
        lq[lr & 15][pt][sl] = make_float4(h.x*m.x, h.y*m.y, h.z*m.z, h.w*m.w);
        lmb[lr & 15][pt][sl] = (m.x != 0.f ? 1u : 0u)
                             | (m.y != 0.f ? 0x100u : 0u)
                             | (m.z != 0.f ? 0x10000u : 0u)
                             | (m.w != 0.f ? 0x1000000u : 0u);
    }
    prefetch_sr(0);
    __syncthreads();

    for (int s = 0; s < SPB; ++s) {
        // ---- consume sr regs -> pe/p2 (masks from LDS rows staged earlier) ----
        float pe[2][12], p2[2][12];
        #pragma unroll
        for (int step = 0; step < 2; ++step) {
            const int lr = 4 * s + 2 * step + rsel;
            const int ms = (lr + 3) & 15;
            const unsigned w0 = lmb[ms][0][l], w1 = lmb[ms][1][l];
            const unsigned w2 = lmb[ms][2][l], w3 = lmb[ms][0][l1];
            float mcf[16];
            dec4(w0, mcf); dec4(w1, mcf + 4); dec4(w2, mcf + 8); dec4(w3, mcf + 12);
            const float4* S = step ? sB : sA;
            const float sf[16] = {S[0].x,S[0].y,S[0].z,S[0].w,
                                  S[1].x,S[1].y,S[1].z,S[1].w,
                                  S[2].x,S[2].y,S[2].z,S[2].w,
                                  S[3].x,S[3].y,S[3].z,S[3].w};
            #pragma unroll
            for (int t = 0; t < 12; ++t) pe[step][t] = sf[t + 3] * mcf[t + 3];
            if (l == 31) {
                pe[step][6] = 0.f; pe[step][7] = 0.f; pe[step][8]  = 0.f;
                pe[step][9] = 0.f; pe[step][10] = 0.f; pe[step][11] = 0.f;
            }
            #pragma unroll
            for (int t = 0; t < 12; ++t) p2[step][t] = pe[step][t] * pe[step][t];
        }

        // ---- issue next-stripe global loads (write-late, consume-next-stripe) ----
        float4 ph = make_float4(0,0,0,0), pm = make_float4(0,0,0,0);
        const bool doStage = (tid < 384) && (s < SPB - 1);
        const int  slr = 4 * s + 10 + ssub;
        if (doStage) {
            int ir = c0 + slr; if (ir > IMG - 1) ir = IMG - 1;
            ph = hb4[(size_t)ir * IMG4 + sc];
            pm = mb4[(size_t)ir * IMG4 + sc];
        }
        if (s < SPB - 1) prefetch_sr(s + 1);

        // ---- compute: 2 steps x 2 rows, wave w = shift i ----
        #pragma unroll
        for (int step = 0; step < 2; ++step) {
            const int lr = 4 * s + 2 * step + rsel;
            if (lr < vrows) {
                const int qs = (lr + w) & 15;
                const float4 Q0 = lq[qs][0][l];
                const float4 Q1 = lq[qs][1][l];
                const float4 Q2 = lq[qs][2][l];
                const float4 Q3 = lq[qs][0][l1];
                const float4 Q4 = lq[qs][1][l1];
                const unsigned u0 = lmb[qs][0][l];
                const unsigned u1 = lmb[qs][1][l];
                const unsigned u2 = lmb[qs][2][l];
                const unsigned u3 = lmb[qs][0][l1];
                const unsigned u4 = lmb[qs][1][l1];
                const float qf[20] = {Q0.x,Q0.y,Q0.z,Q0.w, Q1.x,Q1.y,Q1.z,Q1.w,
                                      Q2.x,Q2.y,Q2.z,Q2.w, Q3.x,Q3.y,Q3.z,Q3.w,
                                      Q4.x,Q4.y,Q4.z,Q4.w};
                float mf[20];
                dec4(u0, mf); dec4(u1, mf + 4); dec4(u2, mf + 8);
                dec4(u3, mf + 12); dec4(u4, mf + 16);
                // NOTE: lane 31's qf/mf[12..19] are garbage (wrapped slot) but
                // only meet pe/p2 entries that were zeroed.

                aTm += (float)(__popc(u0) + __popc(u1) + __popc(u2));
                #pragma unroll
                for (int t = 0; t < 12; ++t) {
                    aTq += qf[t];
                    aTq2 = fmaf(qf[t], qf[t], aTq2);
                }
                if (w == 0) {
                    #pragma unroll
                    for (int t = 0; t < 12; ++t) aSp += pe[step][t];
                }
                #pragma unroll
                for (int t = 0; t < 12; ++t) {
                    const float p = pe[step][t], pp = p2[step][t];
                    #pragma unroll
                    for (int j = 0; j < 7; ++j) {
                        aA[j] = fmaf(p,  qf[t + j], aA[j]);
                        aB[j] = fmaf(pp, mf[t + j], aB[j]);
                        aC[j] = fmaf(p,  mf[t + j], aC[j]);
                    }
                }
            }
        }

        // ---- edge cols: lanes 0..11 of each wave, own shift w ----
        if (lane < 12) {
            #pragma unroll
            for (int y = 0; y < 4; ++y) {
                const int lr = 4 * s + y;
                if (lr < vrows) {
                    const int qs2 = (lr + w) & 15;
                    const float qv = ((const float*)&lq[qs2][ept][esl])[esub];
                    const float mv = (float)((lmb[qs2][ept][esl] >> (8 * esub)) & 255u);
                    eM += mv;
                    eQ += qv;
                    eQ2 = fmaf(qv, qv, eQ2);
                }
            }
        }

        // ---- write-late stage into slots disjoint from this stripe's reads ----
        if (doStage) {
            lq[slr & 15][spt][ssl] = make_float4(ph.x*pm.x, ph.y*pm.y, ph.z*pm.z, ph.w*pm.w);
            lmb[slr & 15][spt][ssl] = (pm.x != 0.f ? 1u : 0u)
                                    | (pm.y != 0.f ? 0x100u : 0u)
                                    | (pm.z != 0.f ? 0x10000u : 0u)
                                    | (pm.w != 0.f ? 0x1000000u : 0u);
        }
        __syncthreads();     // single barrier per stripe
    }

    // ---- per-wave reduction, direct record writes ----
    float* po = part + ((size_t)b * NGRP + grp) * PSTR;
    float vals[24];
    #pragma unroll
    for (int j = 0; j < 7; ++j) { vals[j] = aA[j]; vals[7+j] = aB[j]; vals[14+j] = aC[j]; }
    vals[21] = aTm; vals[22] = aTq; vals[23] = aTq2;
    #pragma unroll
    for (int k = 0; k < 24; ++k) {
        const float v = wave_sum_f(vals[k]);
        if (lane == 0) {
            int off;
            if      (k <  7) off = w*7 + k;              // A[i][j]
            else if (k < 14) off = 49 + w*7 + (k-7);     // B
            else if (k < 21) off = 98 + w*7 + (k-14);    // C
            else if (k == 21) off = 147 + w;             // Tm(i)
            else if (k == 22) off = 154 + w;             // Tq(i)
            else              off = 161 + w;             // Tq2(i)
            po[off] = v;
        }
    }
    {
        const float sp = wave_sum_f(aSp);
        if (w == 0 && lane == 0) po[168] = sp;
    }
    if (lane < 12) {
        po[169 + w*12 + lane] = eM;
        po[253 + w*12 + lane] = eQ;
        po[337 + w*12 + lane] = eQ2;
    }
}

__global__ __launch_bounds__(64)
void mse_kernel(const float* __restrict__ part, double* __restrict__ bmin)
{
    const int b = blockIdx.x;
    const int s = threadIdx.x;           // shifts 0..48 active
    double mse = 1e300;
    if (s < 49) {
        const int i = s / 7, j = s % 7;
        double A=0, Bc=0, Cc=0, Tm=0, Tq=0, Tq2=0, Sp=0;
        for (int g = 0; g < NGRP; ++g) {
            const float* p = part + ((size_t)b * NGRP + g) * PSTR;
            A  += p[      i*7 + j];
            Bc += p[ 49 + i*7 + j];
            Cc += p[ 98 + i*7 + j];
            Tm += p[147 + i];
            Tq += p[154 + i];
            Tq2+= p[161 + i];
            Sp += p[168];
            #pragma unroll
            for (int t = 0; t < 12; ++t) {
                if (t < j || t >= j + 6) {   // col outside x-window [j, j+377]
                    Tm  -= p[169 + i*12 + t];
                    Tq  -= p[253 + i*12 + t];
                    Tq2 -= p[337 + i*12 + t];
                }
            }
        }
        const double bb = (Tq - Sp) / Tm;
        mse = (Tq2 - 2.0*A - 2.0*bb*Tq + Bc + 2.0*bb*Cc + bb*bb*Tm) / Tm;
    }
    for (int off = 32; off; off >>= 1) {
        const double o = __shfl_down(mse, off);
        mse = fmin(mse, o);
    }
    if (s == 0) bmin[b] = mse;
}

__global__ __launch_bounds__(64)
void mean_kernel(const double* __restrict__ bmin, float* __restrict__ out)
{
    double v = bmin[threadIdx.x];
    for (int off = 32; off; off >>= 1) v += __shfl_down(v, off);
    if (threadIdx.x == 0) out[0] = (float)(v / 64.0);
}

extern "C" void kernel_launch(void* const* d_in, const int* in_sizes, int n_in,
                              void* d_out, int out_size, void* d_ws, size_t ws_size,
                              hipStream_t stream) {
    const float* sr = (const float*)d_in[0];
    const float* hr = (const float*)d_in[1];
    const float* mk = (const float*)d_in[2];

    float* part = (float*)d_ws;
    const size_t part_bytes = (size_t)NB * NGRP * PSTR * sizeof(float);  // 1302528
    double* bmin = (double*)((char*)d_ws + part_bytes);

    corr_kernel<<<dim3(NB * NGRP), NTH, 0, stream>>>(sr, hr, mk, part);
    mse_kernel<<<dim3(NB), 64, 0, stream>>>(part, bmin);
    mean_kernel<<<dim3(1), 64, 0, stream>>>(bmin, (float*)d_out);
}